// Round 1
// baseline (478.053 us; speedup 1.0000x reference)
//
#include <hip/hip_runtime.h>
#include <cstddef>

#define N_NODES 16384
#define N_EDGES 131072
#define BGR 256
#define NF 64
#define EF 32
#define GF 16

#define EPB 32   // edges per block
#define NPB 16   // nodes per block

// ---------------------------------------------------------------- edge block
// e1 = relu(ef @ We1 + be1)                        [E,256]
// scatter-mean prep: agg_e1[recv] += e1, cnt_recv[recv] += 1
// e2 = relu(e1 @ We2 + gf[edge_graph] @ Weg2 + be2) [E,128]
// agg_e2_recv[recv] += e2 ; agg_e2_graph[edge_graph] += e2 (block-reduced)
extern "C" __global__ void __launch_bounds__(256)
k_edge(const float* __restrict__ edge_feats,
       const float* __restrict__ global_feats,
       const int* __restrict__ receivers,
       const int* __restrict__ edge_graph,
       const float* __restrict__ We1, const float* __restrict__ be1,
       const float* __restrict__ We2, const float* __restrict__ Weg2,
       const float* __restrict__ be2,
       float* __restrict__ agg_e1, float* __restrict__ cnt_recv,
       float* __restrict__ agg_e2_recv, float* __restrict__ agg_e2_graph,
       float* __restrict__ cnt_eg)
{
    __shared__ float ef[EPB][EF];     // 4 KB
    __shared__ float e1s[EPB][256];   // 32 KB
    __shared__ float red[2][128];

    const int tid = threadIdx.x;
    const int e0  = blockIdx.x * EPB;

    for (int i = tid; i < EPB * EF; i += 256)
        (&ef[0][0])[i] = edge_feats[(size_t)e0 * EF + i];
    __syncthreads();

    // ---- e1: thread owns output column c = tid (256 cols)
    {
        const int c = tid;
        float w[EF];
        #pragma unroll
        for (int k = 0; k < EF; ++k) w[k] = We1[k * 256 + c];
        const float b = be1[c];
        for (int e = 0; e < EPB; ++e) {
            float acc = b;
            #pragma unroll
            for (int k = 0; k < EF; ++k) acc = fmaf(ef[e][k], w[k], acc);
            acc = fmaxf(acc, 0.0f);
            e1s[e][c] = acc;
            atomicAdd(&agg_e1[(size_t)receivers[e0 + e] * 256 + c], acc);
        }
    }
    if (tid < EPB) atomicAdd(&cnt_recv[receivers[e0 + tid]], 1.0f);
    __syncthreads();

    // ---- e2: thread (eh, c2); each thread does 16 edges for one of 128 cols
    const int c2 = tid & 127;
    const int eh = tid >> 7;
    float acc[EPB / 2];
    {
        const float b2 = be2[c2];
        #pragma unroll
        for (int i = 0; i < EPB / 2; ++i) acc[i] = b2;
    }
    for (int kc = 0; kc < 256; kc += 32) {
        float w[32];
        #pragma unroll
        for (int k = 0; k < 32; ++k) w[k] = We2[(kc + k) * 128 + c2];
        #pragma unroll
        for (int i = 0; i < EPB / 2; ++i) {
            const int e = 2 * i + eh;
            float a = acc[i];
            #pragma unroll
            for (int k = 0; k < 32; ++k) a = fmaf(e1s[e][kc + k], w[k], a);
            acc[i] = a;
        }
    }
    {
        float wg[GF];
        #pragma unroll
        for (int j = 0; j < GF; ++j) wg[j] = Weg2[j * 128 + c2];
        #pragma unroll
        for (int i = 0; i < EPB / 2; ++i) {
            const int e = 2 * i + eh;
            const int gidx = edge_graph[e0 + e];
            const float* gv = &global_feats[gidx * GF];
            float a = acc[i];
            #pragma unroll
            for (int j = 0; j < GF; ++j) a = fmaf(gv[j], wg[j], a);
            a = fmaxf(a, 0.0f);
            acc[i] = a;
            atomicAdd(&agg_e2_recv[(size_t)receivers[e0 + e] * 128 + c2], a);
        }
    }
    // ---- graph scatter (edge_graph is sorted -> fast path is block-uniform)
    const int g0 = edge_graph[e0];
    const bool uni = (edge_graph[e0 + EPB - 1] == g0);
    if (uni) {
        float p = 0.0f;
        #pragma unroll
        for (int i = 0; i < EPB / 2; ++i) p += acc[i];
        red[eh][c2] = p;
        __syncthreads();
        if (tid < 128) atomicAdd(&agg_e2_graph[g0 * 128 + tid], red[0][tid] + red[1][tid]);
        if (tid == 0)  atomicAdd(&cnt_eg[g0], (float)EPB);
    } else {
        #pragma unroll
        for (int i = 0; i < EPB / 2; ++i) {
            const int e = 2 * i + eh;
            atomicAdd(&agg_e2_graph[edge_graph[e0 + e] * 128 + c2], acc[i]);
        }
        if (tid < EPB) atomicAdd(&cnt_eg[edge_graph[e0 + tid]], 1.0f);
    }
}

// ---------------------------------------------------------------- node block
// n1 = relu(nf @ Wn1 + (agg_e1/cnt) @ Win1 + bn1)                  [N,256]
// n2 = relu(n1 @ Wn2 + (agg_e2/cnt) @ Win2 + gf[ng] @ Wng2 + bn2)  [N,128]
// agg_n2[node_graph] += n2 (block-reduced), cnt_ng
extern "C" __global__ void __launch_bounds__(256)
k_node(const float* __restrict__ node_feats,
       const float* __restrict__ global_feats,
       const int* __restrict__ node_graph,
       const float* __restrict__ Wn1, const float* __restrict__ Win1,
       const float* __restrict__ bn1,
       const float* __restrict__ Wn2, const float* __restrict__ Win2,
       const float* __restrict__ Wng2, const float* __restrict__ bn2,
       const float* __restrict__ agg_e1, const float* __restrict__ agg_e2_recv,
       const float* __restrict__ cnt_recv,
       float* __restrict__ agg_n2, float* __restrict__ cnt_ng)
{
    __shared__ float nfs[NPB][NF];    // 4 KB
    __shared__ float a1s[NPB][256];   // 16 KB (reused as a2s [NPB][128])
    __shared__ float n1s[NPB][256];   // 16 KB
    __shared__ float red[2][128];

    const int tid = threadIdx.x;
    const int n0  = blockIdx.x * NPB;

    for (int i = tid; i < NPB * NF; i += 256)
        (&nfs[0][0])[i] = node_feats[(size_t)n0 * NF + i];
    for (int i = tid; i < NPB * 256; i += 256) {
        const int n = i >> 8;
        const float cnt = fmaxf(cnt_recv[n0 + n], 1.0f);
        (&a1s[0][0])[i] = agg_e1[(size_t)n0 * 256 + i] / cnt;
    }
    __syncthreads();

    // ---- n1: thread owns column c = tid
    {
        const int c = tid;
        float acc[NPB];
        const float b = bn1[c];
        #pragma unroll
        for (int n = 0; n < NPB; ++n) acc[n] = b;
        for (int kc = 0; kc < NF; kc += 32) {
            float w[32];
            #pragma unroll
            for (int k = 0; k < 32; ++k) w[k] = Wn1[(kc + k) * 256 + c];
            #pragma unroll
            for (int n = 0; n < NPB; ++n) {
                float a = acc[n];
                #pragma unroll
                for (int k = 0; k < 32; ++k) a = fmaf(nfs[n][kc + k], w[k], a);
                acc[n] = a;
            }
        }
        for (int kc = 0; kc < 256; kc += 32) {
            float w[32];
            #pragma unroll
            for (int k = 0; k < 32; ++k) w[k] = Win1[(kc + k) * 256 + c];
            #pragma unroll
            for (int n = 0; n < NPB; ++n) {
                float a = acc[n];
                #pragma unroll
                for (int k = 0; k < 32; ++k) a = fmaf(a1s[n][kc + k], w[k], a);
                acc[n] = a;
            }
        }
        #pragma unroll
        for (int n = 0; n < NPB; ++n) n1s[n][c] = fmaxf(acc[n], 0.0f);
    }
    __syncthreads();

    float* a2s = &a1s[0][0];   // [NPB][128]
    for (int i = tid; i < NPB * 128; i += 256) {
        const int n = i >> 7;
        const float cnt = fmaxf(cnt_recv[n0 + n], 1.0f);
        a2s[i] = agg_e2_recv[(size_t)n0 * 128 + i] / cnt;
    }
    __syncthreads();

    // ---- n2: thread (eh, c2); 8 nodes per thread
    const int c2 = tid & 127;
    const int eh = tid >> 7;
    float acc2[NPB / 2];
    {
        const float b = bn2[c2];
        #pragma unroll
        for (int i = 0; i < NPB / 2; ++i) acc2[i] = b;
    }
    for (int kc = 0; kc < 256; kc += 32) {
        float w[32];
        #pragma unroll
        for (int k = 0; k < 32; ++k) w[k] = Wn2[(kc + k) * 128 + c2];
        #pragma unroll
        for (int i = 0; i < NPB / 2; ++i) {
            const int n = 2 * i + eh;
            float a = acc2[i];
            #pragma unroll
            for (int k = 0; k < 32; ++k) a = fmaf(n1s[n][kc + k], w[k], a);
            acc2[i] = a;
        }
    }
    for (int kc = 0; kc < 128; kc += 32) {
        float w[32];
        #pragma unroll
        for (int k = 0; k < 32; ++k) w[k] = Win2[(kc + k) * 128 + c2];
        #pragma unroll
        for (int i = 0; i < NPB / 2; ++i) {
            const int n = 2 * i + eh;
            float a = acc2[i];
            #pragma unroll
            for (int k = 0; k < 32; ++k) a = fmaf(a2s[n * 128 + kc + k], w[k], a);
            acc2[i] = a;
        }
    }
    {
        float wg[GF];
        #pragma unroll
        for (int j = 0; j < GF; ++j) wg[j] = Wng2[j * 128 + c2];
        #pragma unroll
        for (int i = 0; i < NPB / 2; ++i) {
            const int n = 2 * i + eh;
            const int gidx = node_graph[n0 + n];
            const float* gv = &global_feats[gidx * GF];
            float a = acc2[i];
            #pragma unroll
            for (int j = 0; j < GF; ++j) a = fmaf(gv[j], wg[j], a);
            a = fmaxf(a, 0.0f);
            acc2[i] = a;
        }
    }
    const int g0 = node_graph[n0];
    const bool uni = (node_graph[n0 + NPB - 1] == g0);
    if (uni) {
        float p = 0.0f;
        #pragma unroll
        for (int i = 0; i < NPB / 2; ++i) p += acc2[i];
        red[eh][c2] = p;
        __syncthreads();
        if (tid < 128) atomicAdd(&agg_n2[g0 * 128 + tid], red[0][tid] + red[1][tid]);
        if (tid == 0)  atomicAdd(&cnt_ng[g0], (float)NPB);
    } else {
        #pragma unroll
        for (int i = 0; i < NPB / 2; ++i) {
            const int n = 2 * i + eh;
            atomicAdd(&agg_n2[node_graph[n0 + n] * 128 + c2], acc2[i]);
        }
        if (tid < NPB) atomicAdd(&cnt_ng[node_graph[n0 + tid]], 1.0f);
    }
}

// -------------------------------------------------------------- global block
extern "C" __global__ void __launch_bounds__(256)
k_global(const float* __restrict__ global_feats,
         const float* __restrict__ Ugn, const float* __restrict__ Uge,
         const float* __restrict__ Ugg, const float* __restrict__ bg,
         const float* __restrict__ Wm, const float* __restrict__ bm,
         const float* __restrict__ Ws, const float* __restrict__ bs,
         const float* __restrict__ agg_n2, const float* __restrict__ cnt_ng,
         const float* __restrict__ agg_e2g, const float* __restrict__ cnt_eg,
         float* __restrict__ out)
{
    __shared__ float mn[128], me[128], gs[256];
    const int b = blockIdx.x;
    const int tid = threadIdx.x;
    const float rn = 1.0f / fmaxf(cnt_ng[b], 1.0f);
    const float re = 1.0f / fmaxf(cnt_eg[b], 1.0f);
    if (tid < 128) mn[tid] = agg_n2[b * 128 + tid] * rn;
    else           me[tid - 128] = agg_e2g[b * 128 + (tid - 128)] * re;
    __syncthreads();

    const int h = tid;   // H = 256
    float u = bg[h];
    for (int k = 0; k < 128; ++k) u = fmaf(mn[k], Ugn[k * 256 + h], u);
    for (int k = 0; k < 128; ++k) u = fmaf(me[k], Uge[k * 256 + h], u);
    #pragma unroll
    for (int j = 0; j < GF; ++j) u = fmaf(global_feats[b * GF + j], Ugg[j * 256 + h], u);
    gs[h] = fmaxf(u, 0.0f);
    __syncthreads();

    if (tid < 16) {
        const int a = tid & 7;
        const int which = tid >> 3;      // 0 = mean, 1 = log_std
        const float* W = which ? Ws : Wm;
        float acc = which ? bs[a] : bm[a];
        for (int k = 0; k < 256; ++k) acc = fmaf(gs[k], W[k * 8 + a], acc);
        if (which) acc = fminf(fmaxf(acc, -20.0f), 2.0f);
        out[which * 2048 + b * 8 + a] = acc;
    }
}

extern "C" void kernel_launch(void* const* d_in, const int* in_sizes, int n_in,
                              void* d_out, int out_size, void* d_ws, size_t ws_size,
                              hipStream_t stream)
{
    (void)in_sizes; (void)n_in; (void)out_size; (void)ws_size;
    const float* node_feats   = (const float*)d_in[0];
    const float* edge_feats   = (const float*)d_in[1];
    const float* global_feats = (const float*)d_in[2];
    const int*   receivers    = (const int*)d_in[3];
    const int*   node_graph   = (const int*)d_in[4];
    const int*   edge_graph   = (const int*)d_in[5];
    const float* We1 = (const float*)d_in[6];
    const float* be1 = (const float*)d_in[7];
    const float* Wn1 = (const float*)d_in[8];
    const float* Win1= (const float*)d_in[9];
    const float* bn1 = (const float*)d_in[10];
    const float* We2 = (const float*)d_in[11];
    const float* Weg2= (const float*)d_in[12];
    const float* be2 = (const float*)d_in[13];
    const float* Wn2 = (const float*)d_in[14];
    const float* Win2= (const float*)d_in[15];
    const float* Wng2= (const float*)d_in[16];
    const float* bn2 = (const float*)d_in[17];
    const float* Ugn = (const float*)d_in[18];
    const float* Uge = (const float*)d_in[19];
    const float* Ugg = (const float*)d_in[20];
    const float* bg  = (const float*)d_in[21];
    const float* Wm  = (const float*)d_in[22];
    const float* bm  = (const float*)d_in[23];
    const float* Ws  = (const float*)d_in[24];
    const float* bs  = (const float*)d_in[25];

    float* ws = (float*)d_ws;
    float* agg_e1      = ws;
    float* agg_e2_recv = agg_e1      + (size_t)N_NODES * 256;
    float* agg_e2_g    = agg_e2_recv + (size_t)N_NODES * 128;
    float* agg_n2      = agg_e2_g    + (size_t)BGR * 128;
    float* cnt_recv    = agg_n2      + (size_t)BGR * 128;
    float* cnt_eg      = cnt_recv    + N_NODES;
    float* cnt_ng      = cnt_eg      + BGR;
    const size_t zfloats = (size_t)N_NODES * 256 + (size_t)N_NODES * 128
                         + (size_t)BGR * 128 * 2 + N_NODES + 2 * BGR;
    hipMemsetAsync(d_ws, 0, zfloats * sizeof(float), stream);

    k_edge<<<N_EDGES / EPB, 256, 0, stream>>>(
        edge_feats, global_feats, receivers, edge_graph,
        We1, be1, We2, Weg2, be2,
        agg_e1, cnt_recv, agg_e2_recv, agg_e2_g, cnt_eg);
    k_node<<<N_NODES / NPB, 256, 0, stream>>>(
        node_feats, global_feats, node_graph,
        Wn1, Win1, bn1, Wn2, Win2, Wng2, bn2,
        agg_e1, agg_e2_recv, cnt_recv, agg_n2, cnt_ng);
    k_global<<<BGR, 256, 0, stream>>>(
        global_feats, Ugn, Uge, Ugg, bg, Wm, bm, Ws, bs,
        agg_n2, cnt_ng, agg_e2_g, cnt_eg, (float*)d_out);
}

// Round 2
// 360.566 us; speedup vs baseline: 1.3258x; 1.3258x over previous
//
#include <hip/hip_runtime.h>
#include <cstddef>

#define N_NODES 16384
#define N_EDGES 131072
#define BGR 256
#define NF 64
#define EF 32
#define GF 16

typedef __attribute__((ext_vector_type(8))) short bf16x8;
typedef __attribute__((ext_vector_type(4))) float f32x4;

#define MFMA16(a, b, c) __builtin_amdgcn_mfma_f32_16x16x32_bf16((a), (b), (c), 0, 0, 0)

__device__ inline unsigned short f2bf(float f) {
    unsigned u = __builtin_bit_cast(unsigned, f);
    u += 0x7FFFu + ((u >> 16) & 1u);   // round-to-nearest-even
    return (unsigned short)(u >> 16);
}

__device__ inline bf16x8 pack8(float4 f0, float4 f1, float s) {
    bf16x8 a;
    a[0] = (short)f2bf(f0.x * s); a[1] = (short)f2bf(f0.y * s);
    a[2] = (short)f2bf(f0.z * s); a[3] = (short)f2bf(f0.w * s);
    a[4] = (short)f2bf(f1.x * s); a[5] = (short)f2bf(f1.y * s);
    a[6] = (short)f2bf(f1.z * s); a[7] = (short)f2bf(f1.w * s);
    return a;
}

// ------------------------------------------------------------ weight packing
// W [K][N] row-major f32 -> bf16 B-frags: frag (kt,nt), lane l, elem j =
// W[kt*32 + (l>>4)*8 + j][nt*16 + (l&15)], stored contiguously (16B/lane).
extern "C" __global__ void __launch_bounds__(64)
k_pack(const float* __restrict__ We1, const float* __restrict__ We2,
       const float* __restrict__ Wn1, const float* __restrict__ Win1,
       const float* __restrict__ Wn2, const float* __restrict__ Win2,
       unsigned short* We1p, unsigned short* We2p, unsigned short* Wn1p,
       unsigned short* Win1p, unsigned short* Wn2p, unsigned short* Win2p)
{
    const int bid = blockIdx.x, l = threadIdx.x;
    const float* W; unsigned short* P; int N, t;
    if      (bid < 16)  { W = We1;  P = We1p;  N = 256; t = bid;       }
    else if (bid < 80)  { W = We2;  P = We2p;  N = 128; t = bid - 16;  }
    else if (bid < 112) { W = Wn1;  P = Wn1p;  N = 256; t = bid - 80;  }
    else if (bid < 240) { W = Win1; P = Win1p; N = 256; t = bid - 112; }
    else if (bid < 304) { W = Wn2;  P = Wn2p;  N = 128; t = bid - 240; }
    else                { W = Win2; P = Win2p; N = 128; t = bid - 304; }
    const int NT = N / 16;
    const int kt = t / NT, nt = t % NT;
    const int k0 = kt * 32 + (l >> 4) * 8;
    const int col = nt * 16 + (l & 15);
    unsigned short* dst = P + ((size_t)t * 64 + l) * 8;
    #pragma unroll
    for (int j = 0; j < 8; ++j) dst[j] = f2bf(W[(size_t)(k0 + j) * N + col]);
}

// gproj_e[g][c] = gf[g] @ Weg2 + be2 ; gproj_n[g][c] = gf[g] @ Wng2 + bn2
extern "C" __global__ void __launch_bounds__(128)
k_gproj(const float* __restrict__ gf,
        const float* __restrict__ Weg2, const float* __restrict__ be2,
        const float* __restrict__ Wng2, const float* __restrict__ bn2,
        float* __restrict__ gproj_e, float* __restrict__ gproj_n)
{
    const int b = blockIdx.x, t = threadIdx.x;
    float ge = be2[t], gn = bn2[t];
    #pragma unroll
    for (int j = 0; j < GF; ++j) {
        const float g = gf[b * GF + j];
        ge = fmaf(g, Weg2[j * 128 + t], ge);
        gn = fmaf(g, Wng2[j * 128 + t], gn);
    }
    gproj_e[b * 128 + t] = ge;
    gproj_n[b * 128 + t] = gn;
}

// ---------------------------------------------------------------- edge block
// 64 edges/block, 4 waves; wave w owns rows w*16..w*16+15 (M-tile).
extern "C" __global__ void __launch_bounds__(256, 4)
k_edge(const float* __restrict__ edge_feats,
       const int* __restrict__ receivers,
       const int* __restrict__ edge_graph,
       const unsigned short* __restrict__ We1p,
       const unsigned short* __restrict__ We2p,
       const float* __restrict__ be1,
       const float* __restrict__ gproj_e,
       float* __restrict__ agg_e1, float* __restrict__ cnt_recv,
       float* __restrict__ agg_e2_recv, float* __restrict__ agg_e2_graph,
       float* __restrict__ cnt_eg)
{
    __shared__ __align__(16) unsigned short e1s[64 * 256];   // 32 KB, swizzled
    __shared__ float red[4][128];

    const int tid = threadIdx.x;
    const int wave = tid >> 6, l = tid & 63;
    const int lr = l & 15, lq = l >> 4;
    const int e0 = blockIdx.x * 64;

    const int rowAl = wave * 16 + lr;         // local A row
    const int rowA  = e0 + rowAl;             // global edge id for A
    int rC[4], recvC[4], egC[4];              // C rows for this lane
    #pragma unroll
    for (int i = 0; i < 4; ++i) {
        rC[i]    = wave * 16 + lq * 4 + i;
        recvC[i] = receivers[e0 + rC[i]];
        egC[i]   = edge_graph[e0 + rC[i]];
    }

    // ---- e1 = relu(ef @ We1 + be1), M=64 N=256 K=32 ----
    bf16x8 aE;
    {
        const float* src = edge_feats + (size_t)rowA * EF + lq * 8;
        aE = pack8(*(const float4*)src, *(const float4*)(src + 4), 1.0f);
    }
    char* e1b = (char*)e1s;
    #pragma unroll
    for (int nt = 0; nt < 16; ++nt) {
        bf16x8 b = *(const bf16x8*)(We1p + ((size_t)nt * 64 + l) * 8);
        f32x4 c = {0.f, 0.f, 0.f, 0.f};
        c = MFMA16(aE, b, c);
        const int col = nt * 16 + lr;
        const float bias = be1[col];
        #pragma unroll
        for (int i = 0; i < 4; ++i) {
            float v = fmaxf(c[i] + bias, 0.f);
            atomicAdd(&agg_e1[(size_t)recvC[i] * 256 + col], v);
            const int row = rC[i];
            *(unsigned short*)(e1b + row * 512 + ((col * 2) ^ ((row & 7) << 4))) = f2bf(v);
        }
    }
    if (tid < 64) atomicAdd(&cnt_recv[receivers[e0 + tid]], 1.0f);
    __syncthreads();

    // ---- e2 = relu(e1 @ We2 + gproj_e[eg]), M=64 N=128 K=256 ----
    f32x4 acc[8];
    #pragma unroll
    for (int nt = 0; nt < 8; ++nt) acc[nt] = (f32x4){0.f, 0.f, 0.f, 0.f};
    #pragma unroll
    for (int kt = 0; kt < 8; ++kt) {
        bf16x8 a = *(const bf16x8*)(e1b + rowAl * 512 +
                                    ((kt * 64 + lq * 16) ^ ((rowAl & 7) << 4)));
        #pragma unroll
        for (int nt = 0; nt < 8; ++nt) {
            bf16x8 b = *(const bf16x8*)(We2p + ((size_t)(kt * 8 + nt) * 64 + l) * 8);
            acc[nt] = MFMA16(a, b, acc[nt]);
        }
    }

    const int g0 = edge_graph[e0];
    const bool uni = (edge_graph[e0 + 63] == g0);
    float p[8];
    #pragma unroll
    for (int nt = 0; nt < 8; ++nt) p[nt] = 0.f;
    #pragma unroll
    for (int nt = 0; nt < 8; ++nt) {
        const int col = nt * 16 + lr;
        #pragma unroll
        for (int i = 0; i < 4; ++i) {
            float v = acc[nt][i] + gproj_e[(size_t)egC[i] * 128 + col];
            v = fmaxf(v, 0.f);
            atomicAdd(&agg_e2_recv[(size_t)recvC[i] * 128 + col], v);
            if (uni) p[nt] += v;
            else     atomicAdd(&agg_e2_graph[(size_t)egC[i] * 128 + col], v);
        }
    }
    if (uni) {
        #pragma unroll
        for (int nt = 0; nt < 8; ++nt) {
            float s = p[nt];
            s += __shfl_xor(s, 16, 64);
            s += __shfl_xor(s, 32, 64);
            if (lq == 0) red[wave][nt * 16 + lr] = s;
        }
        __syncthreads();
        if (tid < 128)
            atomicAdd(&agg_e2_graph[(size_t)g0 * 128 + tid],
                      red[0][tid] + red[1][tid] + red[2][tid] + red[3][tid]);
        if (tid == 0) atomicAdd(&cnt_eg[g0], 64.0f);
    } else {
        if (tid < 64) atomicAdd(&cnt_eg[edge_graph[e0 + tid]], 1.0f);
    }
}

// ---------------------------------------------------------------- node block
extern "C" __global__ void __launch_bounds__(256, 2)
k_node(const float* __restrict__ node_feats,
       const int* __restrict__ node_graph,
       const unsigned short* __restrict__ Wn1p,
       const unsigned short* __restrict__ Win1p,
       const unsigned short* __restrict__ Wn2p,
       const unsigned short* __restrict__ Win2p,
       const float* __restrict__ bn1,
       const float* __restrict__ gproj_n,
       const float* __restrict__ agg_e1,
       const float* __restrict__ agg_e2_recv,
       const float* __restrict__ cnt_recv,
       float* __restrict__ agg_n2, float* __restrict__ cnt_ng)
{
    __shared__ __align__(16) unsigned short n1s[64 * 256];   // 32 KB, swizzled
    const int tid = threadIdx.x;
    const int wave = tid >> 6, l = tid & 63;
    const int lr = l & 15, lq = l >> 4;
    const int n0 = blockIdx.x * 64;
    const int rowAl = wave * 16 + lr;
    const int rowA  = n0 + rowAl;
    const float rc = 1.0f / fmaxf(cnt_recv[rowA], 1.0f);
    int rC[4], ngC[4];
    #pragma unroll
    for (int i = 0; i < 4; ++i) {
        rC[i]  = wave * 16 + lq * 4 + i;
        ngC[i] = node_graph[n0 + rC[i]];
    }

    // ---- n1 = relu(nf @ Wn1 + (agg_e1/cnt) @ Win1 + bn1), N=256 K=64+256 ----
    f32x4 acc[16];
    #pragma unroll
    for (int nt = 0; nt < 16; ++nt) acc[nt] = (f32x4){0.f, 0.f, 0.f, 0.f};
    #pragma unroll
    for (int kt = 0; kt < 2; ++kt) {
        const float* src = node_feats + (size_t)rowA * NF + kt * 32 + lq * 8;
        bf16x8 a = pack8(*(const float4*)src, *(const float4*)(src + 4), 1.0f);
        #pragma unroll
        for (int nt = 0; nt < 16; ++nt)
            acc[nt] = MFMA16(a, *(const bf16x8*)(Wn1p + ((size_t)(kt * 16 + nt) * 64 + l) * 8), acc[nt]);
    }
    #pragma unroll
    for (int kt = 0; kt < 8; ++kt) {
        const float* src = agg_e1 + (size_t)rowA * 256 + kt * 32 + lq * 8;
        bf16x8 a = pack8(*(const float4*)src, *(const float4*)(src + 4), rc);
        #pragma unroll
        for (int nt = 0; nt < 16; ++nt)
            acc[nt] = MFMA16(a, *(const bf16x8*)(Win1p + ((size_t)(kt * 16 + nt) * 64 + l) * 8), acc[nt]);
    }
    char* n1b = (char*)n1s;
    #pragma unroll
    for (int nt = 0; nt < 16; ++nt) {
        const int col = nt * 16 + lr;
        const float bias = bn1[col];
        #pragma unroll
        for (int i = 0; i < 4; ++i) {
            float v = fmaxf(acc[nt][i] + bias, 0.f);
            const int row = rC[i];
            *(unsigned short*)(n1b + row * 512 + ((col * 2) ^ ((row & 7) << 4))) = f2bf(v);
        }
    }
    __syncthreads();

    // ---- n2 = relu(n1 @ Wn2 + (agg_e2/cnt) @ Win2 + gproj_n[ng]), N=128 K=256+128 ----
    f32x4 acc2[8];
    #pragma unroll
    for (int nt = 0; nt < 8; ++nt) acc2[nt] = (f32x4){0.f, 0.f, 0.f, 0.f};
    #pragma unroll
    for (int kt = 0; kt < 8; ++kt) {
        bf16x8 a = *(const bf16x8*)(n1b + rowAl * 512 +
                                    ((kt * 64 + lq * 16) ^ ((rowAl & 7) << 4)));
        #pragma unroll
        for (int nt = 0; nt < 8; ++nt)
            acc2[nt] = MFMA16(a, *(const bf16x8*)(Wn2p + ((size_t)(kt * 8 + nt) * 64 + l) * 8), acc2[nt]);
    }
    #pragma unroll
    for (int kt = 0; kt < 4; ++kt) {
        const float* src = agg_e2_recv + (size_t)rowA * 128 + kt * 32 + lq * 8;
        bf16x8 a = pack8(*(const float4*)src, *(const float4*)(src + 4), rc);
        #pragma unroll
        for (int nt = 0; nt < 8; ++nt)
            acc2[nt] = MFMA16(a, *(const bf16x8*)(Win2p + ((size_t)(kt * 8 + nt) * 64 + l) * 8), acc2[nt]);
    }
    #pragma unroll
    for (int nt = 0; nt < 8; ++nt) {
        const int col = nt * 16 + lr;
        #pragma unroll
        for (int i = 0; i < 4; ++i) {
            float v = acc2[nt][i] + gproj_n[(size_t)ngC[i] * 128 + col];
            v = fmaxf(v, 0.f);
            atomicAdd(&agg_n2[(size_t)ngC[i] * 128 + col], v);
        }
    }
    if (tid < 64) atomicAdd(&cnt_ng[node_graph[n0 + tid]], 1.0f);
}

// -------------------------------------------------------------- global block
extern "C" __global__ void __launch_bounds__(256)
k_global(const float* __restrict__ global_feats,
         const float* __restrict__ Ugn, const float* __restrict__ Uge,
         const float* __restrict__ Ugg, const float* __restrict__ bg,
         const float* __restrict__ Wm, const float* __restrict__ bm,
         const float* __restrict__ Ws, const float* __restrict__ bs,
         const float* __restrict__ agg_n2, const float* __restrict__ cnt_ng,
         const float* __restrict__ agg_e2g, const float* __restrict__ cnt_eg,
         float* __restrict__ out)
{
    __shared__ float mn[128], me[128], gs[256];
    const int b = blockIdx.x;
    const int tid = threadIdx.x;
    const float rn = 1.0f / fmaxf(cnt_ng[b], 1.0f);
    const float re = 1.0f / fmaxf(cnt_eg[b], 1.0f);
    if (tid < 128) mn[tid] = agg_n2[b * 128 + tid] * rn;
    else           me[tid - 128] = agg_e2g[b * 128 + (tid - 128)] * re;
    __syncthreads();

    const int h = tid;   // H = 256
    float u = bg[h];
    for (int k = 0; k < 128; ++k) u = fmaf(mn[k], Ugn[k * 256 + h], u);
    for (int k = 0; k < 128; ++k) u = fmaf(me[k], Uge[k * 256 + h], u);
    #pragma unroll
    for (int j = 0; j < GF; ++j) u = fmaf(global_feats[b * GF + j], Ugg[j * 256 + h], u);
    gs[h] = fmaxf(u, 0.0f);
    __syncthreads();

    if (tid < 16) {
        const int a = tid & 7;
        const int which = tid >> 3;      // 0 = mean, 1 = log_std
        const float* W = which ? Ws : Wm;
        float acc = which ? bs[a] : bm[a];
        for (int k = 0; k < 256; ++k) acc = fmaf(gs[k], W[k * 8 + a], acc);
        if (which) acc = fminf(fmaxf(acc, -20.0f), 2.0f);
        out[which * 2048 + b * 8 + a] = acc;
    }
}

extern "C" void kernel_launch(void* const* d_in, const int* in_sizes, int n_in,
                              void* d_out, int out_size, void* d_ws, size_t ws_size,
                              hipStream_t stream)
{
    (void)in_sizes; (void)n_in; (void)out_size; (void)ws_size;
    const float* node_feats   = (const float*)d_in[0];
    const float* edge_feats   = (const float*)d_in[1];
    const float* global_feats = (const float*)d_in[2];
    const int*   receivers    = (const int*)d_in[3];
    const int*   node_graph   = (const int*)d_in[4];
    const int*   edge_graph   = (const int*)d_in[5];
    const float* We1 = (const float*)d_in[6];
    const float* be1 = (const float*)d_in[7];
    const float* Wn1 = (const float*)d_in[8];
    const float* Win1= (const float*)d_in[9];
    const float* bn1 = (const float*)d_in[10];
    const float* We2 = (const float*)d_in[11];
    const float* Weg2= (const float*)d_in[12];
    const float* be2 = (const float*)d_in[13];
    const float* Wn2 = (const float*)d_in[14];
    const float* Win2= (const float*)d_in[15];
    const float* Wng2= (const float*)d_in[16];
    const float* bn2 = (const float*)d_in[17];
    const float* Ugn = (const float*)d_in[18];
    const float* Uge = (const float*)d_in[19];
    const float* Ugg = (const float*)d_in[20];
    const float* bg  = (const float*)d_in[21];
    const float* Wm  = (const float*)d_in[22];
    const float* bm  = (const float*)d_in[23];
    const float* Ws  = (const float*)d_in[24];
    const float* bs  = (const float*)d_in[25];

    float* ws = (float*)d_ws;
    float* agg_e1      = ws;
    float* agg_e2_recv = agg_e1      + (size_t)N_NODES * 256;
    float* agg_e2_g    = agg_e2_recv + (size_t)N_NODES * 128;
    float* agg_n2      = agg_e2_g    + (size_t)BGR * 128;
    float* cnt_recv    = agg_n2      + (size_t)BGR * 128;
    float* cnt_eg      = cnt_recv    + N_NODES;
    float* cnt_ng      = cnt_eg      + BGR;
    float* gproj_e     = cnt_ng      + BGR;
    float* gproj_n     = gproj_e     + (size_t)BGR * 128;
    unsigned short* We1p  = (unsigned short*)(gproj_n + (size_t)BGR * 128);
    unsigned short* We2p  = We1p  + 32 * 256;
    unsigned short* Wn1p  = We2p  + 256 * 128;
    unsigned short* Win1p = Wn1p  + 64 * 256;
    unsigned short* Wn2p  = Win1p + 256 * 256;
    unsigned short* Win2p = Wn2p  + 256 * 128;

    const size_t zfloats = (size_t)N_NODES * 256 + (size_t)N_NODES * 128
                         + (size_t)BGR * 128 * 2 + N_NODES + 2 * BGR;
    hipMemsetAsync(d_ws, 0, zfloats * sizeof(float), stream);

    k_pack<<<336, 64, 0, stream>>>(We1, We2, Wn1, Win1, Wn2, Win2,
                                   We1p, We2p, Wn1p, Win1p, Wn2p, Win2p);
    k_gproj<<<BGR, 128, 0, stream>>>(global_feats, Weg2, be2, Wng2, bn2,
                                     gproj_e, gproj_n);
    k_edge<<<N_EDGES / 64, 256, 0, stream>>>(
        edge_feats, receivers, edge_graph, We1p, We2p, be1, gproj_e,
        agg_e1, cnt_recv, agg_e2_recv, agg_e2_g, cnt_eg);
    k_node<<<N_NODES / 64, 256, 0, stream>>>(
        node_feats, node_graph, Wn1p, Win1p, Wn2p, Win2p, bn1, gproj_n,
        agg_e1, agg_e2_recv, cnt_recv, agg_n2, cnt_ng);
    k_global<<<BGR, 256, 0, stream>>>(
        global_feats, Ugn, Uge, Ugg, bg, Wm, bm, Ws, bs,
        agg_n2, cnt_ng, agg_e2_g, cnt_eg, (float*)d_out);
}

// Round 3
// 323.638 us; speedup vs baseline: 1.4771x; 1.1141x over previous
//
#include <hip/hip_runtime.h>
#include <cstddef>

#define N_NODES 16384
#define N_EDGES 131072
#define BGR 256
#define NF 64
#define EF 32
#define GF 16

typedef __attribute__((ext_vector_type(8))) short bf16x8;
typedef __attribute__((ext_vector_type(4))) float f32x4;

#define MFMA16(a, b, c) __builtin_amdgcn_mfma_f32_16x16x32_bf16((a), (b), (c), 0, 0, 0)

__device__ inline unsigned short f2bf(float f) {
    unsigned u = __builtin_bit_cast(unsigned, f);
    u += 0x7FFFu + ((u >> 16) & 1u);   // round-to-nearest-even
    return (unsigned short)(u >> 16);
}
__device__ inline float bflo(unsigned x) { return __builtin_bit_cast(float, x << 16); }
__device__ inline float bfhi(unsigned x) { return __builtin_bit_cast(float, x & 0xFFFF0000u); }

__device__ inline bf16x8 pack8(float4 f0, float4 f1) {
    bf16x8 a;
    a[0] = (short)f2bf(f0.x); a[1] = (short)f2bf(f0.y);
    a[2] = (short)f2bf(f0.z); a[3] = (short)f2bf(f0.w);
    a[4] = (short)f2bf(f1.x); a[5] = (short)f2bf(f1.y);
    a[6] = (short)f2bf(f1.z); a[7] = (short)f2bf(f1.w);
    return a;
}

// ------------------------------------------------------------ weight packing
// W [K][N] row-major f32 -> bf16 B-frags: frag (kt,nt), lane l, elem j =
// W[kt*32 + (l>>4)*8 + j][nt*16 + (l&15)], stored contiguously (16B/lane).
extern "C" __global__ void __launch_bounds__(64)
k_pack(const float* __restrict__ We1, const float* __restrict__ We2,
       const float* __restrict__ Wn1, const float* __restrict__ Win1,
       const float* __restrict__ Wn2, const float* __restrict__ Win2,
       unsigned short* We1p, unsigned short* We2p, unsigned short* Wn1p,
       unsigned short* Win1p, unsigned short* Wn2p, unsigned short* Win2p)
{
    const int bid = blockIdx.x, l = threadIdx.x;
    const float* W; unsigned short* P; int N, t;
    if      (bid < 16)  { W = We1;  P = We1p;  N = 256; t = bid;       }
    else if (bid < 80)  { W = We2;  P = We2p;  N = 128; t = bid - 16;  }
    else if (bid < 112) { W = Wn1;  P = Wn1p;  N = 256; t = bid - 80;  }
    else if (bid < 240) { W = Win1; P = Win1p; N = 256; t = bid - 112; }
    else if (bid < 304) { W = Wn2;  P = Wn2p;  N = 128; t = bid - 240; }
    else                { W = Win2; P = Win2p; N = 128; t = bid - 304; }
    const int NT = N / 16;
    const int kt = t / NT, nt = t % NT;
    const int k0 = kt * 32 + (l >> 4) * 8;
    const int col = nt * 16 + (l & 15);
    unsigned short* dst = P + ((size_t)t * 64 + l) * 8;
    #pragma unroll
    for (int j = 0; j < 8; ++j) dst[j] = f2bf(W[(size_t)(k0 + j) * N + col]);
}

// gproj_e[g][c] = gf[g] @ Weg2 + be2 ; gproj_n[g][c] = gf[g] @ Wng2 + bn2
extern "C" __global__ void __launch_bounds__(128)
k_gproj(const float* __restrict__ gf,
        const float* __restrict__ Weg2, const float* __restrict__ be2,
        const float* __restrict__ Wng2, const float* __restrict__ bn2,
        float* __restrict__ gproj_e, float* __restrict__ gproj_n)
{
    const int b = blockIdx.x, t = threadIdx.x;
    float ge = be2[t], gn = bn2[t];
    #pragma unroll
    for (int j = 0; j < GF; ++j) {
        const float g = gf[b * GF + j];
        ge = fmaf(g, Weg2[j * 128 + t], ge);
        gn = fmaf(g, Wng2[j * 128 + t], gn);
    }
    gproj_e[b * 128 + t] = ge;
    gproj_n[b * 128 + t] = gn;
}

// ------------------------------------------------- counting sort (3 kernels)
extern "C" __global__ void __launch_bounds__(256)
k_hist(const int* __restrict__ receivers, const int* __restrict__ node_graph,
       const int* __restrict__ edge_graph,
       int* cntR, int* cntNG, int* cntEG)
{
    const int i = blockIdx.x * 256 + threadIdx.x;
    if (i < N_EDGES) {
        atomicAdd(&cntR[receivers[i]], 1);
        atomicAdd(&cntEG[edge_graph[i]], 1);
    }
    if (i < N_NODES) atomicAdd(&cntNG[node_graph[i]], 1);
}

extern "C" __global__ void __launch_bounds__(256)
k_scan(const int* __restrict__ cntR, const int* __restrict__ cntNG,
       const int* __restrict__ cntEG,
       int* offR, int* offN, int* offE)
{
    __shared__ int sm[256];
    const int t = threadIdx.x;
    if (blockIdx.x == 0) {
        int s = 0;
        for (int j = 0; j < 64; ++j) s += cntR[t * 64 + j];
        sm[t] = s; __syncthreads();
        for (int o = 1; o < 256; o <<= 1) {
            int x = (t >= o) ? sm[t - o] : 0;
            __syncthreads(); sm[t] += x; __syncthreads();
        }
        int run = sm[t] - s;
        for (int j = 0; j < 64; ++j) { offR[t * 64 + j] = run; run += cntR[t * 64 + j]; }
        if (t == 255) offR[16384] = sm[255];
    } else {
        const int* c = (blockIdx.x == 1) ? cntNG : cntEG;
        int* dst     = (blockIdx.x == 1) ? offN  : offE;
        int s = c[t];
        sm[t] = s; __syncthreads();
        for (int o = 1; o < 256; o <<= 1) {
            int x = (t >= o) ? sm[t - o] : 0;
            __syncthreads(); sm[t] += x; __syncthreads();
        }
        dst[t] = sm[t] - s;
        if (t == 255) dst[256] = sm[255];
    }
}

extern "C" __global__ void __launch_bounds__(256)
k_scatter(const int* __restrict__ receivers, const int* __restrict__ offR,
          int* curR, int* perm)
{
    const int i = blockIdx.x * 256 + threadIdx.x;
    if (i < N_EDGES) {
        const int r = receivers[i];
        const int pos = offR[r] + atomicAdd(&curR[r], 1);
        perm[pos] = i;
    }
}

// ---------------------------------------------------------------- edge block
// e1 = relu(ef@We1+be1) -> LDS + HBM bf16 [E][256]
// e2 = relu(e1@We2 + gproj_e[eg]) -> HBM bf16 [E][128].  No atomics.
extern "C" __global__ void __launch_bounds__(256, 4)
k_edge(const float* __restrict__ edge_feats,
       const int* __restrict__ edge_graph,
       const unsigned short* __restrict__ We1p,
       const unsigned short* __restrict__ We2p,
       const float* __restrict__ be1,
       const float* __restrict__ gproj_e,
       unsigned short* __restrict__ e1g,
       unsigned short* __restrict__ e2g)
{
    __shared__ __align__(16) unsigned short e1s[64 * 256];   // 32 KB, swizzled
    const int tid = threadIdx.x;
    const int wave = tid >> 6, l = tid & 63;
    const int lr = l & 15, lq = l >> 4;
    const int e0 = blockIdx.x * 64;
    const int rowAl = wave * 16 + lr;
    const int rowA  = e0 + rowAl;
    int rC[4], egC[4];
    #pragma unroll
    for (int i = 0; i < 4; ++i) {
        rC[i]  = wave * 16 + lq * 4 + i;
        egC[i] = edge_graph[e0 + rC[i]];
    }

    // ---- e1: M=64 N=256 K=32 ----
    bf16x8 aE;
    {
        const float* src = edge_feats + (size_t)rowA * EF + lq * 8;
        aE = pack8(*(const float4*)src, *(const float4*)(src + 4));
    }
    char* e1b = (char*)e1s;
    #pragma unroll
    for (int nt = 0; nt < 16; ++nt) {
        bf16x8 b = *(const bf16x8*)(We1p + ((size_t)nt * 64 + l) * 8);
        f32x4 c = {0.f, 0.f, 0.f, 0.f};
        c = MFMA16(aE, b, c);
        const int col = nt * 16 + lr;
        const float bias = be1[col];
        #pragma unroll
        for (int i = 0; i < 4; ++i) {
            float v = fmaxf(c[i] + bias, 0.f);
            const int row = rC[i];
            *(unsigned short*)(e1b + row * 512 + ((col * 2) ^ ((row & 7) << 4))) = f2bf(v);
        }
    }
    __syncthreads();

    // ---- dump e1 LDS -> HBM, coalesced 16B/lane ----
    #pragma unroll
    for (int it = 0; it < 8; ++it) {
        const int flat = it * 4096 + tid * 16;
        const int row = flat >> 9, colb = flat & 511;
        bf16x8 v = *(const bf16x8*)(e1b + row * 512 + (colb ^ ((row & 7) << 4)));
        *(bf16x8*)(e1g + (size_t)(e0 + row) * 256 + (colb >> 1)) = v;
    }

    // ---- e2: M=64 N=128 K=256 ----
    f32x4 acc[8];
    #pragma unroll
    for (int nt = 0; nt < 8; ++nt) acc[nt] = (f32x4){0.f, 0.f, 0.f, 0.f};
    #pragma unroll
    for (int kt = 0; kt < 8; ++kt) {
        bf16x8 a = *(const bf16x8*)(e1b + rowAl * 512 +
                                    ((kt * 64 + lq * 16) ^ ((rowAl & 7) << 4)));
        #pragma unroll
        for (int nt = 0; nt < 8; ++nt) {
            bf16x8 b = *(const bf16x8*)(We2p + ((size_t)(kt * 8 + nt) * 64 + l) * 8);
            acc[nt] = MFMA16(a, b, acc[nt]);
        }
    }
    __syncthreads();   // all e1s reads complete before reuse as e2 buffer

    #pragma unroll
    for (int nt = 0; nt < 8; ++nt) {
        const int col = nt * 16 + lr;
        #pragma unroll
        for (int i = 0; i < 4; ++i) {
            float v = fmaxf(acc[nt][i] + gproj_e[(size_t)egC[i] * 128 + col], 0.f);
            const int row = rC[i];
            *(unsigned short*)(e1b + row * 256 + ((col * 2) ^ ((row & 7) << 4))) = f2bf(v);
        }
    }
    __syncthreads();
    #pragma unroll
    for (int it = 0; it < 4; ++it) {
        const int flat = it * 4096 + tid * 16;
        const int row = flat >> 8, colb = flat & 255;
        bf16x8 v = *(const bf16x8*)(e1b + row * 256 + (colb ^ ((row & 7) << 4)));
        *(bf16x8*)(e2g + (size_t)(e0 + row) * 128 + (colb >> 1)) = v;
    }
}

// ---------------------------------------------- per-node gather-mean (e1,e2)
// wave per node: mean1[n][256], mean2[n][128] (bf16)
extern "C" __global__ void __launch_bounds__(256)
k_agg(const unsigned short* __restrict__ e1g,
      const unsigned short* __restrict__ e2g,
      const int* __restrict__ offR, const int* __restrict__ perm,
      unsigned short* __restrict__ mean1, unsigned short* __restrict__ mean2)
{
    const int tid = threadIdx.x, wave = tid >> 6, l = tid & 63;
    const int n = blockIdx.x * 4 + wave;
    const int c0 = offR[n], c1 = offR[n + 1];
    float s1[4] = {0.f, 0.f, 0.f, 0.f};
    float s2[2] = {0.f, 0.f};
    for (int e = c0; e < c1; ++e) {
        const int eid = perm[e];
        const uint2 a = *(const uint2*)(e1g + (size_t)eid * 256 + l * 4);
        s1[0] += bflo(a.x); s1[1] += bfhi(a.x);
        s1[2] += bflo(a.y); s1[3] += bfhi(a.y);
        const unsigned b = *(const unsigned*)(e2g + (size_t)eid * 128 + l * 2);
        s2[0] += bflo(b); s2[1] += bfhi(b);
    }
    const float inv = 1.0f / fmaxf((float)(c1 - c0), 1.0f);
    uint2 p;
    p.x = (unsigned)f2bf(s1[0] * inv) | ((unsigned)f2bf(s1[1] * inv) << 16);
    p.y = (unsigned)f2bf(s1[2] * inv) | ((unsigned)f2bf(s1[3] * inv) << 16);
    *(uint2*)(mean1 + (size_t)n * 256 + l * 4) = p;
    *(unsigned*)(mean2 + (size_t)n * 128 + l * 2) =
        (unsigned)f2bf(s2[0] * inv) | ((unsigned)f2bf(s2[1] * inv) << 16);
}

// ---------------------------------------------------------------- node block
// n1 = relu(nf@Wn1 + mean1@Win1 + bn1); n2 = relu(n1@Wn2 + mean2@Win2 + gproj_n[ng])
// n2 -> HBM bf16 [N][128].  No atomics.
extern "C" __global__ void __launch_bounds__(256, 2)
k_node(const float* __restrict__ node_feats,
       const int* __restrict__ node_graph,
       const unsigned short* __restrict__ Wn1p,
       const unsigned short* __restrict__ Win1p,
       const unsigned short* __restrict__ Wn2p,
       const unsigned short* __restrict__ Win2p,
       const float* __restrict__ bn1,
       const float* __restrict__ gproj_n,
       const unsigned short* __restrict__ mean1,
       const unsigned short* __restrict__ mean2,
       unsigned short* __restrict__ n2g)
{
    __shared__ __align__(16) unsigned short n1s[64 * 256];   // 32 KB, swizzled
    const int tid = threadIdx.x;
    const int wave = tid >> 6, l = tid & 63;
    const int lr = l & 15, lq = l >> 4;
    const int n0 = blockIdx.x * 64;
    const int rowAl = wave * 16 + lr;
    const int rowA  = n0 + rowAl;
    int rC[4], ngC[4];
    #pragma unroll
    for (int i = 0; i < 4; ++i) {
        rC[i]  = wave * 16 + lq * 4 + i;
        ngC[i] = node_graph[n0 + rC[i]];
    }

    // ---- n1: N=256, K=64(nf)+256(mean1) ----
    f32x4 acc[16];
    #pragma unroll
    for (int nt = 0; nt < 16; ++nt) acc[nt] = (f32x4){0.f, 0.f, 0.f, 0.f};
    #pragma unroll
    for (int kt = 0; kt < 2; ++kt) {
        const float* src = node_feats + (size_t)rowA * NF + kt * 32 + lq * 8;
        bf16x8 a = pack8(*(const float4*)src, *(const float4*)(src + 4));
        #pragma unroll
        for (int nt = 0; nt < 16; ++nt)
            acc[nt] = MFMA16(a, *(const bf16x8*)(Wn1p + ((size_t)(kt * 16 + nt) * 64 + l) * 8), acc[nt]);
    }
    #pragma unroll
    for (int kt = 0; kt < 8; ++kt) {
        bf16x8 a = *(const bf16x8*)(mean1 + (size_t)rowA * 256 + kt * 32 + lq * 8);
        #pragma unroll
        for (int nt = 0; nt < 16; ++nt)
            acc[nt] = MFMA16(a, *(const bf16x8*)(Win1p + ((size_t)(kt * 16 + nt) * 64 + l) * 8), acc[nt]);
    }
    char* n1b = (char*)n1s;
    #pragma unroll
    for (int nt = 0; nt < 16; ++nt) {
        const int col = nt * 16 + lr;
        const float bias = bn1[col];
        #pragma unroll
        for (int i = 0; i < 4; ++i) {
            float v = fmaxf(acc[nt][i] + bias, 0.f);
            const int row = rC[i];
            *(unsigned short*)(n1b + row * 512 + ((col * 2) ^ ((row & 7) << 4))) = f2bf(v);
        }
    }
    __syncthreads();

    // ---- n2: N=128, K=256(n1)+128(mean2) ----
    f32x4 acc2[8];
    #pragma unroll
    for (int nt = 0; nt < 8; ++nt) acc2[nt] = (f32x4){0.f, 0.f, 0.f, 0.f};
    #pragma unroll
    for (int kt = 0; kt < 8; ++kt) {
        bf16x8 a = *(const bf16x8*)(n1b + rowAl * 512 +
                                    ((kt * 64 + lq * 16) ^ ((rowAl & 7) << 4)));
        #pragma unroll
        for (int nt = 0; nt < 8; ++nt)
            acc2[nt] = MFMA16(a, *(const bf16x8*)(Wn2p + ((size_t)(kt * 8 + nt) * 64 + l) * 8), acc2[nt]);
    }
    #pragma unroll
    for (int kt = 0; kt < 4; ++kt) {
        bf16x8 a = *(const bf16x8*)(mean2 + (size_t)rowA * 128 + kt * 32 + lq * 8);
        #pragma unroll
        for (int nt = 0; nt < 8; ++nt)
            acc2[nt] = MFMA16(a, *(const bf16x8*)(Win2p + ((size_t)(kt * 8 + nt) * 64 + l) * 8), acc2[nt]);
    }
    __syncthreads();   // n1s reads done before reuse
    #pragma unroll
    for (int nt = 0; nt < 8; ++nt) {
        const int col = nt * 16 + lr;
        #pragma unroll
        for (int i = 0; i < 4; ++i) {
            float v = fmaxf(acc2[nt][i] + gproj_n[(size_t)ngC[i] * 128 + col], 0.f);
            const int row = rC[i];
            *(unsigned short*)(n1b + row * 256 + ((col * 2) ^ ((row & 7) << 4))) = f2bf(v);
        }
    }
    __syncthreads();
    #pragma unroll
    for (int it = 0; it < 4; ++it) {
        const int flat = it * 4096 + tid * 16;
        const int row = flat >> 8, colb = flat & 255;
        bf16x8 v = *(const bf16x8*)(n1b + row * 256 + (colb ^ ((row & 7) << 4)));
        *(bf16x8*)(n2g + (size_t)(n0 + row) * 128 + (colb >> 1)) = v;
    }
}

// -------------------------------------------------------------- global block
// per-graph means over contiguous node/edge ranges, then u -> heads
extern "C" __global__ void __launch_bounds__(256)
k_global(const float* __restrict__ global_feats,
         const float* __restrict__ Ugn, const float* __restrict__ Uge,
         const float* __restrict__ Ugg, const float* __restrict__ bg,
         const float* __restrict__ Wm, const float* __restrict__ bm,
         const float* __restrict__ Ws, const float* __restrict__ bs,
         const unsigned short* __restrict__ n2g,
         const unsigned short* __restrict__ e2g,
         const int* __restrict__ offN, const int* __restrict__ offE,
         float* __restrict__ out)
{
    __shared__ float redn[8][128], rede[8][128];
    __shared__ float mn[128], me[128], gs[256];
    const int b = blockIdx.x, tid = threadIdx.x;
    const int c4 = tid & 31, rp = tid >> 5;   // 4 cols/thread, 8-way rows
    float sn[4] = {0.f, 0.f, 0.f, 0.f}, se[4] = {0.f, 0.f, 0.f, 0.f};
    const int nb = offN[b], ne = offN[b + 1];
    for (int r = nb + rp; r < ne; r += 8) {
        const uint2 v = *(const uint2*)(n2g + (size_t)r * 128 + c4 * 4);
        sn[0] += bflo(v.x); sn[1] += bfhi(v.x); sn[2] += bflo(v.y); sn[3] += bfhi(v.y);
    }
    const int eb = offE[b], ee = offE[b + 1];
    for (int r = eb + rp; r < ee; r += 8) {
        const uint2 v = *(const uint2*)(e2g + (size_t)r * 128 + c4 * 4);
        se[0] += bflo(v.x); se[1] += bfhi(v.x); se[2] += bflo(v.y); se[3] += bfhi(v.y);
    }
    #pragma unroll
    for (int j = 0; j < 4; ++j) { redn[rp][c4 * 4 + j] = sn[j]; rede[rp][c4 * 4 + j] = se[j]; }
    __syncthreads();
    if (tid < 128) {
        float s = 0.f;
        #pragma unroll
        for (int k = 0; k < 8; ++k) s += redn[k][tid];
        mn[tid] = s / fmaxf((float)(ne - nb), 1.0f);
    } else {
        const int t = tid - 128;
        float s = 0.f;
        #pragma unroll
        for (int k = 0; k < 8; ++k) s += rede[k][t];
        me[t] = s / fmaxf((float)(ee - eb), 1.0f);
    }
    __syncthreads();

    const int h = tid;   // H = 256
    float u = bg[h];
    for (int k = 0; k < 128; ++k) u = fmaf(mn[k], Ugn[k * 256 + h], u);
    for (int k = 0; k < 128; ++k) u = fmaf(me[k], Uge[k * 256 + h], u);
    #pragma unroll
    for (int j = 0; j < GF; ++j) u = fmaf(global_feats[b * GF + j], Ugg[j * 256 + h], u);
    gs[h] = fmaxf(u, 0.0f);
    __syncthreads();

    if (tid < 16) {
        const int a = tid & 7;
        const int which = tid >> 3;      // 0 = mean, 1 = log_std
        const float* W = which ? Ws : Wm;
        float acc = which ? bs[a] : bm[a];
        for (int k = 0; k < 256; ++k) acc = fmaf(gs[k], W[k * 8 + a], acc);
        if (which) acc = fminf(fmaxf(acc, -20.0f), 2.0f);
        out[which * 2048 + b * 8 + a] = acc;
    }
}

extern "C" void kernel_launch(void* const* d_in, const int* in_sizes, int n_in,
                              void* d_out, int out_size, void* d_ws, size_t ws_size,
                              hipStream_t stream)
{
    (void)in_sizes; (void)n_in; (void)out_size; (void)ws_size;
    const float* node_feats   = (const float*)d_in[0];
    const float* edge_feats   = (const float*)d_in[1];
    const float* global_feats = (const float*)d_in[2];
    const int*   receivers    = (const int*)d_in[3];
    const int*   node_graph   = (const int*)d_in[4];
    const int*   edge_graph   = (const int*)d_in[5];
    const float* We1 = (const float*)d_in[6];
    const float* be1 = (const float*)d_in[7];
    const float* Wn1 = (const float*)d_in[8];
    const float* Win1= (const float*)d_in[9];
    const float* bn1 = (const float*)d_in[10];
    const float* We2 = (const float*)d_in[11];
    const float* Weg2= (const float*)d_in[12];
    const float* be2 = (const float*)d_in[13];
    const float* Wn2 = (const float*)d_in[14];
    const float* Win2= (const float*)d_in[15];
    const float* Wng2= (const float*)d_in[16];
    const float* bn2 = (const float*)d_in[17];
    const float* Ugn = (const float*)d_in[18];
    const float* Uge = (const float*)d_in[19];
    const float* Ugg = (const float*)d_in[20];
    const float* bg  = (const float*)d_in[21];
    const float* Wm  = (const float*)d_in[22];
    const float* bm  = (const float*)d_in[23];
    const float* Ws  = (const float*)d_in[24];
    const float* bs  = (const float*)d_in[25];

    char* p = (char*)d_ws;
    auto alloc = [&](size_t bytes) -> char* {
        char* r = p; p += (bytes + 255) & ~(size_t)255; return r;
    };
    // zeroed region (contiguous, at the front)
    int* cntR  = (int*)alloc(16384 * 4);
    int* cntNG = (int*)alloc(256 * 4);
    int* cntEG = (int*)alloc(256 * 4);
    int* curR  = (int*)alloc(16384 * 4);
    const size_t zero_bytes = (size_t)(p - (char*)d_ws);
    // overwritten-every-call region
    int* offR = (int*)alloc(16385 * 4);
    int* offN = (int*)alloc(257 * 4);
    int* offE = (int*)alloc(257 * 4);
    int* perm = (int*)alloc((size_t)N_EDGES * 4);
    float* gproj_e = (float*)alloc((size_t)BGR * 128 * 4);
    float* gproj_n = (float*)alloc((size_t)BGR * 128 * 4);
    unsigned short* We1p  = (unsigned short*)alloc((size_t)32 * 256 * 2);
    unsigned short* We2p  = (unsigned short*)alloc((size_t)256 * 128 * 2);
    unsigned short* Wn1p  = (unsigned short*)alloc((size_t)64 * 256 * 2);
    unsigned short* Win1p = (unsigned short*)alloc((size_t)256 * 256 * 2);
    unsigned short* Wn2p  = (unsigned short*)alloc((size_t)256 * 128 * 2);
    unsigned short* Win2p = (unsigned short*)alloc((size_t)128 * 128 * 2 * 2);
    unsigned short* e1g   = (unsigned short*)alloc((size_t)N_EDGES * 256 * 2);
    unsigned short* e2g   = (unsigned short*)alloc((size_t)N_EDGES * 128 * 2);
    unsigned short* n2g   = (unsigned short*)alloc((size_t)N_NODES * 128 * 2);
    unsigned short* mean1 = (unsigned short*)alloc((size_t)N_NODES * 256 * 2);
    unsigned short* mean2 = (unsigned short*)alloc((size_t)N_NODES * 128 * 2);

    hipMemsetAsync(d_ws, 0, zero_bytes, stream);

    k_pack<<<368, 64, 0, stream>>>(We1, We2, Wn1, Win1, Wn2, Win2,
                                   We1p, We2p, Wn1p, Win1p, Wn2p, Win2p);
    k_gproj<<<BGR, 128, 0, stream>>>(global_feats, Weg2, be2, Wng2, bn2,
                                     gproj_e, gproj_n);
    k_hist<<<N_EDGES / 256, 256, 0, stream>>>(receivers, node_graph, edge_graph,
                                              cntR, cntNG, cntEG);
    k_scan<<<3, 256, 0, stream>>>(cntR, cntNG, cntEG, offR, offN, offE);
    k_scatter<<<N_EDGES / 256, 256, 0, stream>>>(receivers, offR, curR, perm);
    k_edge<<<N_EDGES / 64, 256, 0, stream>>>(
        edge_feats, edge_graph, We1p, We2p, be1, gproj_e, e1g, e2g);
    k_agg<<<N_NODES / 4, 256, 0, stream>>>(e1g, e2g, offR, perm, mean1, mean2);
    k_node<<<N_NODES / 64, 256, 0, stream>>>(
        node_feats, node_graph, Wn1p, Win1p, Wn2p, Win2p, bn1, gproj_n,
        mean1, mean2, n2g);
    k_global<<<BGR, 256, 0, stream>>>(
        global_feats, Ugn, Uge, Ugg, bg, Wm, bm, Ws, bs,
        n2g, e2g, offN, offE, (float*)d_out);
}

// Round 4
// 157.110 us; speedup vs baseline: 3.0428x; 2.0599x over previous
//
#include <hip/hip_runtime.h>
#include <cstddef>

#define N_NODES 16384
#define N_EDGES 131072
#define BGR 256
#define NF 64
#define EF 32
#define GF 16

typedef __attribute__((ext_vector_type(8))) short bf16x8;
typedef __attribute__((ext_vector_type(4))) float f32x4;

#define MFMA16(a, b, c) __builtin_amdgcn_mfma_f32_16x16x32_bf16((a), (b), (c), 0, 0, 0)

__device__ inline unsigned short f2bf(float f) {
    unsigned u = __builtin_bit_cast(unsigned, f);
    u += 0x7FFFu + ((u >> 16) & 1u);   // round-to-nearest-even
    return (unsigned short)(u >> 16);
}
__device__ inline float bflo(unsigned x) { return __builtin_bit_cast(float, x << 16); }
__device__ inline float bfhi(unsigned x) { return __builtin_bit_cast(float, x & 0xFFFF0000u); }

__device__ inline bf16x8 pack8(float4 f0, float4 f1) {
    bf16x8 a;
    a[0] = (short)f2bf(f0.x); a[1] = (short)f2bf(f0.y);
    a[2] = (short)f2bf(f0.z); a[3] = (short)f2bf(f0.w);
    a[4] = (short)f2bf(f1.x); a[5] = (short)f2bf(f1.y);
    a[6] = (short)f2bf(f1.z); a[7] = (short)f2bf(f1.w);
    return a;
}

// ------------------------------------------------------------ weight packing
// W [K][N] row-major f32 -> bf16 B-frags: frag (kt,nt), lane l, elem j =
// W[kt*32 + (l>>4)*8 + j][nt*16 + (l&15)], stored contiguously (16B/lane).
extern "C" __global__ void __launch_bounds__(64)
k_pack(const float* __restrict__ We1, const float* __restrict__ We2,
       const float* __restrict__ Wn1, const float* __restrict__ Win1,
       const float* __restrict__ Wn2, const float* __restrict__ Win2,
       unsigned short* We1p, unsigned short* We2p, unsigned short* Wn1p,
       unsigned short* Win1p, unsigned short* Wn2p, unsigned short* Win2p)
{
    const int bid = blockIdx.x, l = threadIdx.x;
    const float* W; unsigned short* P; int N, t;
    if      (bid < 16)  { W = We1;  P = We1p;  N = 256; t = bid;       }
    else if (bid < 80)  { W = We2;  P = We2p;  N = 128; t = bid - 16;  }
    else if (bid < 112) { W = Wn1;  P = Wn1p;  N = 256; t = bid - 80;  }
    else if (bid < 240) { W = Win1; P = Win1p; N = 256; t = bid - 112; }
    else if (bid < 304) { W = Wn2;  P = Wn2p;  N = 128; t = bid - 240; }
    else                { W = Win2; P = Win2p; N = 128; t = bid - 304; }
    const int NT = N / 16;
    const int kt = t / NT, nt = t % NT;
    const int k0 = kt * 32 + (l >> 4) * 8;
    const int col = nt * 16 + (l & 15);
    unsigned short* dst = P + ((size_t)t * 64 + l) * 8;
    #pragma unroll
    for (int j = 0; j < 8; ++j) dst[j] = f2bf(W[(size_t)(k0 + j) * N + col]);
}

// gproj_e[g][c] = gf[g] @ Weg2 + be2 ; gproj_n[g][c] = gf[g] @ Wng2 + bn2
extern "C" __global__ void __launch_bounds__(128)
k_gproj(const float* __restrict__ gf,
        const float* __restrict__ Weg2, const float* __restrict__ be2,
        const float* __restrict__ Wng2, const float* __restrict__ bn2,
        float* __restrict__ gproj_e, float* __restrict__ gproj_n)
{
    const int b = blockIdx.x, t = threadIdx.x;
    float ge = be2[t], gn = bn2[t];
    #pragma unroll
    for (int j = 0; j < GF; ++j) {
        const float g = gf[b * GF + j];
        ge = fmaf(g, Weg2[j * 128 + t], ge);
        gn = fmaf(g, Wng2[j * 128 + t], gn);
    }
    gproj_e[b * 128 + t] = ge;
    gproj_n[b * 128 + t] = gn;
}

// --------------------------------------------------------------- counting sort
// receivers histogram — random addresses, low contention, atomics OK.
extern "C" __global__ void __launch_bounds__(256)
k_hist(const int* __restrict__ receivers, int* cntR)
{
    const int i = blockIdx.x * 256 + threadIdx.x;
    if (i < N_EDGES) atomicAdd(&cntR[receivers[i]], 1);
}

// sorted node_graph/edge_graph -> per-graph offsets via binary search (NO atomics)
extern "C" __global__ void __launch_bounds__(256)
k_bounds(const int* __restrict__ node_graph, const int* __restrict__ edge_graph,
         int* offN, int* offE)
{
    const int g = threadIdx.x;
    const int* arr = blockIdx.x ? edge_graph : node_graph;
    int* dst       = blockIdx.x ? offE       : offN;
    const int len  = blockIdx.x ? N_EDGES    : N_NODES;
    // lower_bound: first i with arr[i] >= g
    int lo = 0, hi = len;
    while (lo < hi) {
        const int mid = (lo + hi) >> 1;
        if (arr[mid] < g) lo = mid + 1; else hi = mid;
    }
    dst[g] = lo;
    if (g == 0) dst[256] = len;
}

extern "C" __global__ void __launch_bounds__(256)
k_scan(const int* __restrict__ cntR, int* offR)
{
    __shared__ int sm[256];
    const int t = threadIdx.x;
    int s = 0;
    for (int j = 0; j < 64; ++j) s += cntR[t * 64 + j];
    sm[t] = s; __syncthreads();
    for (int o = 1; o < 256; o <<= 1) {
        int x = (t >= o) ? sm[t - o] : 0;
        __syncthreads(); sm[t] += x; __syncthreads();
    }
    int run = sm[t] - s;
    for (int j = 0; j < 64; ++j) { offR[t * 64 + j] = run; run += cntR[t * 64 + j]; }
    if (t == 255) offR[16384] = sm[255];
}

extern "C" __global__ void __launch_bounds__(256)
k_scatter(const int* __restrict__ receivers, const int* __restrict__ offR,
          int* curR, int* perm)
{
    const int i = blockIdx.x * 256 + threadIdx.x;
    if (i < N_EDGES) {
        const int r = receivers[i];
        const int pos = offR[r] + atomicAdd(&curR[r], 1);
        perm[pos] = i;
    }
}

// ---------------------------------------------------------------- edge block
// e1 = relu(ef@We1+be1) -> LDS + HBM bf16 [E][256]
// e2 = relu(e1@We2 + gproj_e[eg]) -> HBM bf16 [E][128].  No atomics.
extern "C" __global__ void __launch_bounds__(256, 4)
k_edge(const float* __restrict__ edge_feats,
       const int* __restrict__ edge_graph,
       const unsigned short* __restrict__ We1p,
       const unsigned short* __restrict__ We2p,
       const float* __restrict__ be1,
       const float* __restrict__ gproj_e,
       unsigned short* __restrict__ e1g,
       unsigned short* __restrict__ e2g)
{
    __shared__ __align__(16) unsigned short e1s[64 * 256];   // 32 KB, swizzled
    const int tid = threadIdx.x;
    const int wave = tid >> 6, l = tid & 63;
    const int lr = l & 15, lq = l >> 4;
    const int e0 = blockIdx.x * 64;
    const int rowAl = wave * 16 + lr;
    const int rowA  = e0 + rowAl;
    int rC[4], egC[4];
    #pragma unroll
    for (int i = 0; i < 4; ++i) {
        rC[i]  = wave * 16 + lq * 4 + i;
        egC[i] = edge_graph[e0 + rC[i]];
    }

    // ---- e1: M=64 N=256 K=32 ----
    bf16x8 aE;
    {
        const float* src = edge_feats + (size_t)rowA * EF + lq * 8;
        aE = pack8(*(const float4*)src, *(const float4*)(src + 4));
    }
    char* e1b = (char*)e1s;
    #pragma unroll
    for (int nt = 0; nt < 16; ++nt) {
        bf16x8 b = *(const bf16x8*)(We1p + ((size_t)nt * 64 + l) * 8);
        f32x4 c = {0.f, 0.f, 0.f, 0.f};
        c = MFMA16(aE, b, c);
        const int col = nt * 16 + lr;
        const float bias = be1[col];
        #pragma unroll
        for (int i = 0; i < 4; ++i) {
            float v = fmaxf(c[i] + bias, 0.f);
            const int row = rC[i];
            *(unsigned short*)(e1b + row * 512 + ((col * 2) ^ ((row & 7) << 4))) = f2bf(v);
        }
    }
    __syncthreads();

    // ---- dump e1 LDS -> HBM, coalesced 16B/lane ----
    #pragma unroll
    for (int it = 0; it < 8; ++it) {
        const int flat = it * 4096 + tid * 16;
        const int row = flat >> 9, colb = flat & 511;
        bf16x8 v = *(const bf16x8*)(e1b + row * 512 + (colb ^ ((row & 7) << 4)));
        *(bf16x8*)(e1g + (size_t)(e0 + row) * 256 + (colb >> 1)) = v;
    }

    // ---- e2: M=64 N=128 K=256 ----
    f32x4 acc[8];
    #pragma unroll
    for (int nt = 0; nt < 8; ++nt) acc[nt] = (f32x4){0.f, 0.f, 0.f, 0.f};
    #pragma unroll
    for (int kt = 0; kt < 8; ++kt) {
        bf16x8 a = *(const bf16x8*)(e1b + rowAl * 512 +
                                    ((kt * 64 + lq * 16) ^ ((rowAl & 7) << 4)));
        #pragma unroll
        for (int nt = 0; nt < 8; ++nt) {
            bf16x8 b = *(const bf16x8*)(We2p + ((size_t)(kt * 8 + nt) * 64 + l) * 8);
            acc[nt] = MFMA16(a, b, acc[nt]);
        }
    }
    __syncthreads();   // all e1s reads complete before reuse as e2 buffer

    #pragma unroll
    for (int nt = 0; nt < 8; ++nt) {
        const int col = nt * 16 + lr;
        #pragma unroll
        for (int i = 0; i < 4; ++i) {
            float v = fmaxf(acc[nt][i] + gproj_e[(size_t)egC[i] * 128 + col], 0.f);
            const int row = rC[i];
            *(unsigned short*)(e1b + row * 256 + ((col * 2) ^ ((row & 7) << 4))) = f2bf(v);
        }
    }
    __syncthreads();
    #pragma unroll
    for (int it = 0; it < 4; ++it) {
        const int flat = it * 4096 + tid * 16;
        const int row = flat >> 8, colb = flat & 255;
        bf16x8 v = *(const bf16x8*)(e1b + row * 256 + (colb ^ ((row & 7) << 4)));
        *(bf16x8*)(e2g + (size_t)(e0 + row) * 128 + (colb >> 1)) = v;
    }
}

// ---------------------------------------------- per-node gather-mean (e1,e2)
// wave per node: mean1[n][256], mean2[n][128] (bf16)
extern "C" __global__ void __launch_bounds__(256)
k_agg(const unsigned short* __restrict__ e1g,
      const unsigned short* __restrict__ e2g,
      const int* __restrict__ offR, const int* __restrict__ perm,
      unsigned short* __restrict__ mean1, unsigned short* __restrict__ mean2)
{
    const int tid = threadIdx.x, wave = tid >> 6, l = tid & 63;
    const int n = blockIdx.x * 4 + wave;
    const int c0 = offR[n], c1 = offR[n + 1];
    float s1[4] = {0.f, 0.f, 0.f, 0.f};
    float s2[2] = {0.f, 0.f};
    for (int e = c0; e < c1; ++e) {
        const int eid = perm[e];
        const uint2 a = *(const uint2*)(e1g + (size_t)eid * 256 + l * 4);
        s1[0] += bflo(a.x); s1[1] += bfhi(a.x);
        s1[2] += bflo(a.y); s1[3] += bfhi(a.y);
        const unsigned b = *(const unsigned*)(e2g + (size_t)eid * 128 + l * 2);
        s2[0] += bflo(b); s2[1] += bfhi(b);
    }
    const float inv = 1.0f / fmaxf((float)(c1 - c0), 1.0f);
    uint2 p;
    p.x = (unsigned)f2bf(s1[0] * inv) | ((unsigned)f2bf(s1[1] * inv) << 16);
    p.y = (unsigned)f2bf(s1[2] * inv) | ((unsigned)f2bf(s1[3] * inv) << 16);
    *(uint2*)(mean1 + (size_t)n * 256 + l * 4) = p;
    *(unsigned*)(mean2 + (size_t)n * 128 + l * 2) =
        (unsigned)f2bf(s2[0] * inv) | ((unsigned)f2bf(s2[1] * inv) << 16);
}

// ---------------------------------------------------------------- node block
// n1 = relu(nf@Wn1 + mean1@Win1 + bn1); n2 = relu(n1@Wn2 + mean2@Win2 + gproj_n[ng])
// n2 -> HBM bf16 [N][128].  No atomics.
extern "C" __global__ void __launch_bounds__(256, 2)
k_node(const float* __restrict__ node_feats,
       const int* __restrict__ node_graph,
       const unsigned short* __restrict__ Wn1p,
       const unsigned short* __restrict__ Win1p,
       const unsigned short* __restrict__ Wn2p,
       const unsigned short* __restrict__ Win2p,
       const float* __restrict__ bn1,
       const float* __restrict__ gproj_n,
       const unsigned short* __restrict__ mean1,
       const unsigned short* __restrict__ mean2,
       unsigned short* __restrict__ n2g)
{
    __shared__ __align__(16) unsigned short n1s[64 * 256];   // 32 KB, swizzled
    const int tid = threadIdx.x;
    const int wave = tid >> 6, l = tid & 63;
    const int lr = l & 15, lq = l >> 4;
    const int n0 = blockIdx.x * 64;
    const int rowAl = wave * 16 + lr;
    const int rowA  = n0 + rowAl;
    int rC[4], ngC[4];
    #pragma unroll
    for (int i = 0; i < 4; ++i) {
        rC[i]  = wave * 16 + lq * 4 + i;
        ngC[i] = node_graph[n0 + rC[i]];
    }

    // ---- n1: N=256, K=64(nf)+256(mean1) ----
    f32x4 acc[16];
    #pragma unroll
    for (int nt = 0; nt < 16; ++nt) acc[nt] = (f32x4){0.f, 0.f, 0.f, 0.f};
    #pragma unroll
    for (int kt = 0; kt < 2; ++kt) {
        const float* src = node_feats + (size_t)rowA * NF + kt * 32 + lq * 8;
        bf16x8 a = pack8(*(const float4*)src, *(const float4*)(src + 4));
        #pragma unroll
        for (int nt = 0; nt < 16; ++nt)
            acc[nt] = MFMA16(a, *(const bf16x8*)(Wn1p + ((size_t)(kt * 16 + nt) * 64 + l) * 8), acc[nt]);
    }
    #pragma unroll
    for (int kt = 0; kt < 8; ++kt) {
        bf16x8 a = *(const bf16x8*)(mean1 + (size_t)rowA * 256 + kt * 32 + lq * 8);
        #pragma unroll
        for (int nt = 0; nt < 16; ++nt)
            acc[nt] = MFMA16(a, *(const bf16x8*)(Win1p + ((size_t)(kt * 16 + nt) * 64 + l) * 8), acc[nt]);
    }
    char* n1b = (char*)n1s;
    #pragma unroll
    for (int nt = 0; nt < 16; ++nt) {
        const int col = nt * 16 + lr;
        const float bias = bn1[col];
        #pragma unroll
        for (int i = 0; i < 4; ++i) {
            float v = fmaxf(acc[nt][i] + bias, 0.f);
            const int row = rC[i];
            *(unsigned short*)(n1b + row * 512 + ((col * 2) ^ ((row & 7) << 4))) = f2bf(v);
        }
    }
    __syncthreads();

    // ---- n2: N=128, K=256(n1)+128(mean2) ----
    f32x4 acc2[8];
    #pragma unroll
    for (int nt = 0; nt < 8; ++nt) acc2[nt] = (f32x4){0.f, 0.f, 0.f, 0.f};
    #pragma unroll
    for (int kt = 0; kt < 8; ++kt) {
        bf16x8 a = *(const bf16x8*)(n1b + rowAl * 512 +
                                    ((kt * 64 + lq * 16) ^ ((rowAl & 7) << 4)));
        #pragma unroll
        for (int nt = 0; nt < 8; ++nt)
            acc2[nt] = MFMA16(a, *(const bf16x8*)(Wn2p + ((size_t)(kt * 8 + nt) * 64 + l) * 8), acc2[nt]);
    }
    #pragma unroll
    for (int kt = 0; kt < 4; ++kt) {
        bf16x8 a = *(const bf16x8*)(mean2 + (size_t)rowA * 128 + kt * 32 + lq * 8);
        #pragma unroll
        for (int nt = 0; nt < 8; ++nt)
            acc2[nt] = MFMA16(a, *(const bf16x8*)(Win2p + ((size_t)(kt * 8 + nt) * 64 + l) * 8), acc2[nt]);
    }
    __syncthreads();   // n1s reads done before reuse
    #pragma unroll
    for (int nt = 0; nt < 8; ++nt) {
        const int col = nt * 16 + lr;
        #pragma unroll
        for (int i = 0; i < 4; ++i) {
            float v = fmaxf(acc2[nt][i] + gproj_n[(size_t)ngC[i] * 128 + col], 0.f);
            const int row = rC[i];
            *(unsigned short*)(n1b + row * 256 + ((col * 2) ^ ((row & 7) << 4))) = f2bf(v);
        }
    }
    __syncthreads();
    #pragma unroll
    for (int it = 0; it < 4; ++it) {
        const int flat = it * 4096 + tid * 16;
        const int row = flat >> 8, colb = flat & 255;
        bf16x8 v = *(const bf16x8*)(n1b + row * 256 + (colb ^ ((row & 7) << 4)));
        *(bf16x8*)(n2g + (size_t)(n0 + row) * 128 + (colb >> 1)) = v;
    }
}

// -------------------------------------------------------------- global block
// per-graph means over contiguous node/edge ranges, then u -> heads
extern "C" __global__ void __launch_bounds__(256)
k_global(const float* __restrict__ global_feats,
         const float* __restrict__ Ugn, const float* __restrict__ Uge,
         const float* __restrict__ Ugg, const float* __restrict__ bg,
         const float* __restrict__ Wm, const float* __restrict__ bm,
         const float* __restrict__ Ws, const float* __restrict__ bs,
         const unsigned short* __restrict__ n2g,
         const unsigned short* __restrict__ e2g,
         const int* __restrict__ offN, const int* __restrict__ offE,
         float* __restrict__ out)
{
    __shared__ float redn[8][128], rede[8][128];
    __shared__ float mn[128], me[128], gs[256];
    const int b = blockIdx.x, tid = threadIdx.x;
    const int c4 = tid & 31, rp = tid >> 5;   // 4 cols/thread, 8-way rows
    float sn[4] = {0.f, 0.f, 0.f, 0.f}, se[4] = {0.f, 0.f, 0.f, 0.f};
    const int nb = offN[b], ne = offN[b + 1];
    for (int r = nb + rp; r < ne; r += 8) {
        const uint2 v = *(const uint2*)(n2g + (size_t)r * 128 + c4 * 4);
        sn[0] += bflo(v.x); sn[1] += bfhi(v.x); sn[2] += bflo(v.y); sn[3] += bfhi(v.y);
    }
    const int eb = offE[b], ee = offE[b + 1];
    for (int r = eb + rp; r < ee; r += 8) {
        const uint2 v = *(const uint2*)(e2g + (size_t)r * 128 + c4 * 4);
        se[0] += bflo(v.x); se[1] += bfhi(v.x); se[2] += bflo(v.y); se[3] += bfhi(v.y);
    }
    #pragma unroll
    for (int j = 0; j < 4; ++j) { redn[rp][c4 * 4 + j] = sn[j]; rede[rp][c4 * 4 + j] = se[j]; }
    __syncthreads();
    if (tid < 128) {
        float s = 0.f;
        #pragma unroll
        for (int k = 0; k < 8; ++k) s += redn[k][tid];
        mn[tid] = s / fmaxf((float)(ne - nb), 1.0f);
    } else {
        const int t = tid - 128;
        float s = 0.f;
        #pragma unroll
        for (int k = 0; k < 8; ++k) s += rede[k][t];
        me[t] = s / fmaxf((float)(ee - eb), 1.0f);
    }
    __syncthreads();

    const int h = tid;   // H = 256
    float u = bg[h];
    for (int k = 0; k < 128; ++k) u = fmaf(mn[k], Ugn[k * 256 + h], u);
    for (int k = 0; k < 128; ++k) u = fmaf(me[k], Uge[k * 256 + h], u);
    #pragma unroll
    for (int j = 0; j < GF; ++j) u = fmaf(global_feats[b * GF + j], Ugg[j * 256 + h], u);
    gs[h] = fmaxf(u, 0.0f);
    __syncthreads();

    if (tid < 16) {
        const int a = tid & 7;
        const int which = tid >> 3;      // 0 = mean, 1 = log_std
        const float* W = which ? Ws : Wm;
        float acc = which ? bs[a] : bm[a];
        for (int k = 0; k < 256; ++k) acc = fmaf(gs[k], W[k * 8 + a], acc);
        if (which) acc = fminf(fmaxf(acc, -20.0f), 2.0f);
        out[which * 2048 + b * 8 + a] = acc;
    }
}

extern "C" void kernel_launch(void* const* d_in, const int* in_sizes, int n_in,
                              void* d_out, int out_size, void* d_ws, size_t ws_size,
                              hipStream_t stream)
{
    (void)in_sizes; (void)n_in; (void)out_size; (void)ws_size;
    const float* node_feats   = (const float*)d_in[0];
    const float* edge_feats   = (const float*)d_in[1];
    const float* global_feats = (const float*)d_in[2];
    const int*   receivers    = (const int*)d_in[3];
    const int*   node_graph   = (const int*)d_in[4];
    const int*   edge_graph   = (const int*)d_in[5];
    const float* We1 = (const float*)d_in[6];
    const float* be1 = (const float*)d_in[7];
    const float* Wn1 = (const float*)d_in[8];
    const float* Win1= (const float*)d_in[9];
    const float* bn1 = (const float*)d_in[10];
    const float* We2 = (const float*)d_in[11];
    const float* Weg2= (const float*)d_in[12];
    const float* be2 = (const float*)d_in[13];
    const float* Wn2 = (const float*)d_in[14];
    const float* Win2= (const float*)d_in[15];
    const float* Wng2= (const float*)d_in[16];
    const float* bn2 = (const float*)d_in[17];
    const float* Ugn = (const float*)d_in[18];
    const float* Uge = (const float*)d_in[19];
    const float* Ugg = (const float*)d_in[20];
    const float* bg  = (const float*)d_in[21];
    const float* Wm  = (const float*)d_in[22];
    const float* bm  = (const float*)d_in[23];
    const float* Ws  = (const float*)d_in[24];
    const float* bs  = (const float*)d_in[25];

    char* p = (char*)d_ws;
    auto alloc = [&](size_t bytes) -> char* {
        char* r = p; p += (bytes + 255) & ~(size_t)255; return r;
    };
    // zeroed region (contiguous, at the front)
    int* cntR  = (int*)alloc(16384 * 4);
    int* curR  = (int*)alloc(16384 * 4);
    const size_t zero_bytes = (size_t)(p - (char*)d_ws);
    // overwritten-every-call region
    int* offR = (int*)alloc(16385 * 4);
    int* offN = (int*)alloc(257 * 4);
    int* offE = (int*)alloc(257 * 4);
    int* perm = (int*)alloc((size_t)N_EDGES * 4);
    float* gproj_e = (float*)alloc((size_t)BGR * 128 * 4);
    float* gproj_n = (float*)alloc((size_t)BGR * 128 * 4);
    unsigned short* We1p  = (unsigned short*)alloc((size_t)32 * 256 * 2);
    unsigned short* We2p  = (unsigned short*)alloc((size_t)256 * 128 * 2);
    unsigned short* Wn1p  = (unsigned short*)alloc((size_t)64 * 256 * 2);
    unsigned short* Win1p = (unsigned short*)alloc((size_t)256 * 256 * 2);
    unsigned short* Wn2p  = (unsigned short*)alloc((size_t)256 * 128 * 2);
    unsigned short* Win2p = (unsigned short*)alloc((size_t)128 * 128 * 2 * 2);
    unsigned short* e1g   = (unsigned short*)alloc((size_t)N_EDGES * 256 * 2);
    unsigned short* e2g   = (unsigned short*)alloc((size_t)N_EDGES * 128 * 2);
    unsigned short* n2g   = (unsigned short*)alloc((size_t)N_NODES * 128 * 2);
    unsigned short* mean1 = (unsigned short*)alloc((size_t)N_NODES * 256 * 2);
    unsigned short* mean2 = (unsigned short*)alloc((size_t)N_NODES * 128 * 2);

    hipMemsetAsync(d_ws, 0, zero_bytes, stream);

    k_pack<<<368, 64, 0, stream>>>(We1, We2, Wn1, Win1, Wn2, Win2,
                                   We1p, We2p, Wn1p, Win1p, Wn2p, Win2p);
    k_gproj<<<BGR, 128, 0, stream>>>(global_feats, Weg2, be2, Wng2, bn2,
                                     gproj_e, gproj_n);
    k_hist<<<N_EDGES / 256, 256, 0, stream>>>(receivers, cntR);
    k_bounds<<<2, 256, 0, stream>>>(node_graph, edge_graph, offN, offE);
    k_scan<<<1, 256, 0, stream>>>(cntR, offR);
    k_scatter<<<N_EDGES / 256, 256, 0, stream>>>(receivers, offR, curR, perm);
    k_edge<<<N_EDGES / 64, 256, 0, stream>>>(
        edge_feats, edge_graph, We1p, We2p, be1, gproj_e, e1g, e2g);
    k_agg<<<N_NODES / 4, 256, 0, stream>>>(e1g, e2g, offR, perm, mean1, mean2);
    k_node<<<N_NODES / 64, 256, 0, stream>>>(
        node_feats, node_graph, Wn1p, Win1p, Wn2p, Win2p, bn1, gproj_n,
        mean1, mean2, n2g);
    k_global<<<BGR, 256, 0, stream>>>(
        global_feats, Ugn, Uge, Ugg, bg, Wm, bm, Ws, bs,
        n2g, e2g, offN, offE, (float*)d_out);
}